// Round 7
// baseline (262.670 us; speedup 1.0000x reference)
//
#include <hip/hip_runtime.h>
#include <hip/hip_bf16.h>

#define NN 50000
#define NPAD 53248              // 13 * 4096, scan padding
#define EE 800000
#define DIM 256
#define NEG_SLOPE 0.2f
#define LOG2E 1.44269504088896f
#define CSTR 50048              // per-XCD counter array stride (NN -> x64 ints)

#define GEMM_BLOCKS 1564        // 391 * 4
#define FILL_BLOCKS 3125
#define MIX_BLOCKS  15625       // 3125 count + 12500 cvt, interleaved 1:4
#define WT_BLOCKS   512
#define PRERED_BLOCKS 208       // NPAD / 256

typedef __attribute__((ext_vector_type(8))) short short8;
typedef __attribute__((ext_vector_type(4))) float f32x4;
typedef __attribute__((ext_vector_type(2))) float v2f;

__device__ __forceinline__ unsigned short f2bf(float f) {
    unsigned u = __float_as_uint(f);
    unsigned r = (u + 0x7fffu + ((u >> 16) & 1u)) >> 16;   // RNE
    return (unsigned short)r;
}
__device__ __forceinline__ float u2f_lo(unsigned u) {      // bf16 in low 16
    return __uint_as_float(u << 16);
}
__device__ __forceinline__ float u2f_hi(unsigned u) {      // bf16 in high 16
    return __uint_as_float(u & 0xffff0000u);
}

// 8-lane sum via DPP (VALU pipe only — no ds_swizzle LDS round trips).
__device__ __forceinline__ float red8(float s) {
    int t;
    t = __builtin_amdgcn_update_dpp(0, __float_as_int(s), 0xB1, 0xF, 0xF, true);
    s += __int_as_float(t);
    t = __builtin_amdgcn_update_dpp(0, __float_as_int(s), 0x4E, 0xF, 0xF, true);
    s += __int_as_float(t);
    t = __builtin_amdgcn_update_dpp(0, __float_as_int(s), 0x141, 0xF, 0xF, true);
    s += __int_as_float(t);
    return s;
}

// ---------------------------------------------------------------------------
// K1: degree count via XCD-LOCAL atomics (workgroup-scope atomicAdd into the
// physical XCD's private partial array — executes in the local TCC, never at
// the slow cross-XCD coherent point; all updaters of array c run on XCD c by
// construction) interleaved 1:4 with x->bf16 cvt; Wt build at the tail.
// rank16[e] = (xcc<<8) | local_rank  (local rank per (xcd,dst) < 256).
// ---------------------------------------------------------------------------
__global__ __launch_bounds__(256) void k_prep_count(
    const float* __restrict__ x, const float* __restrict__ Wl,
    const float* __restrict__ Wr, const int* __restrict__ ei,
    unsigned short* __restrict__ xb, unsigned short* __restrict__ wt,
    unsigned* __restrict__ cnt_x, unsigned short* __restrict__ rank16)
{
    int b = blockIdx.x;
    if (b < MIX_BLOCKS) {
        int g = b / 5;
        if (b - g * 5 == 0) {                              // count role (1 in 5)
            int e = g * 256 + threadIdx.x;                 // g in [0,3125)
            int dst = ei[EE + e];
            unsigned xcc;
            asm volatile("s_getreg_b32 %0, hwreg(HW_REG_XCC_ID)" : "=s"(xcc));
            xcc &= 7u;
            unsigned rl = __hip_atomic_fetch_add(
                &cnt_x[xcc * CSTR + (unsigned)dst], 1u,
                __ATOMIC_RELAXED, __HIP_MEMORY_SCOPE_WORKGROUP);
            rank16[e] = (unsigned short)((xcc << 8) | rl);
        } else {                                           // cvt role (4 in 5)
            int ci = b - g - 1;                            // [0,12500)
            int i = (ci * 256 + threadIdx.x) * 4;
            float4 v = *(const float4*)(x + i);
            ushort4 o;
            o.x = f2bf(v.x); o.y = f2bf(v.y); o.z = f2bf(v.z); o.w = f2bf(v.w);
            *(ushort4*)(xb + i) = o;
        }
    } else {                                               // Wt build
        int idx = (b - MIX_BLOCKS) * 256 + threadIdx.x;
        int n = idx >> 8, k = idx & 255;
        float v = (n < 256) ? Wl[k * 256 + n] : Wr[k * 256 + (n - 256)];
        wt[idx] = f2bf(v);
    }
}

// ---------------------------------------------------------------------------
// K1b: fold the 8 per-XCD partials: cnt_x[c][d] <- exclusive prefix over c
// (within-dst base), tot written into row_st (scanned in place by k_scan).
// One thread per dst, fully coalesced per array. 208 blocks.
// ---------------------------------------------------------------------------
__global__ __launch_bounds__(256) void k_prered(
    unsigned* __restrict__ cnt_x, int* __restrict__ row_st)
{
    int d = blockIdx.x * 256 + threadIdx.x;    // [0, NPAD)
    unsigned s = 0;
    if (d < CSTR) {
#pragma unroll
        for (int c = 0; c < 8; ++c) {
            unsigned v = cnt_x[c * CSTR + d];
            cnt_x[c * CSTR + d] = s;           // within-dst exclusive prefix
            s += v;
        }
    }
    row_st[d] = (int)s;                        // total count (0 beyond NN)
}

// ---------------------------------------------------------------------------
// K2: exclusive prefix sum IN PLACE on row_st (int4-vectorized, 1 block;
// all loads hoisted before any store, so in-place is safe).
// ---------------------------------------------------------------------------
__global__ __launch_bounds__(1024) void k_scan(int* __restrict__ a)
{
    __shared__ int wsum[16];
    int tid = threadIdx.x, lane = tid & 63, wid = tid >> 6;
    int4 v[13];
#pragma unroll
    for (int p = 0; p < 13; ++p)
        v[p] = *(const int4*)(a + p * 4096 + tid * 4);
    int carry = 0;
#pragma unroll
    for (int p = 0; p < 13; ++p) {
        int4 vv = v[p];
        int tsum = vv.x + vv.y + vv.z + vv.w;
        int s = tsum;
#pragma unroll
        for (int off = 1; off < 64; off <<= 1) {
            int t = __shfl_up(s, off, 64);
            if (lane >= off) s += t;
        }
        if (lane == 63) wsum[wid] = s;
        __syncthreads();
        int wpre = 0, tot = 0;
#pragma unroll
        for (int w = 0; w < 16; ++w) {
            int xv = wsum[w];
            tot += xv;
            if (w < wid) wpre += xv;
        }
        int ex = carry + wpre + (s - tsum);
        int4 o;
        o.x = ex;
        o.y = o.x + vv.x;
        o.z = o.y + vv.y;
        o.w = o.z + vv.z;
        *(int4*)(a + p * 4096 + tid * 4) = o;
        carry += tot;
        __syncthreads();
    }
}

// ---------------------------------------------------------------------------
// K3 (fused): blocks [0,1564) MFMA GEMM {xl,xr} = xb @ [Wl|Wr]^T
// overlapped with [1564,4689) CSR fill (scattered-write-bound, NO atomics).
// Fill position: row_start[dst] + within-dst XCD base + local rank.
// Bijective chunked XCD swizzle on GEMM (verified: FETCH 14.5MB, round-5 PMC).
// ---------------------------------------------------------------------------
__global__ __launch_bounds__(256) void k_gemm_fill(
    const unsigned short* __restrict__ xb, const unsigned short* __restrict__ wt,
    const int* __restrict__ ei, const float* __restrict__ ea,
    const int* __restrict__ row_start, const unsigned short* __restrict__ rank16,
    const unsigned* __restrict__ cnt_x,
    unsigned short* __restrict__ xl, unsigned short* __restrict__ xr,
    uint2* __restrict__ edge_rec)
{
    __shared__ short sAB[8192];                 // A: [0,4096) B: [4096,8192)
    int tid = threadIdx.x;

    if (blockIdx.x >= GEMM_BLOCKS) {            // ---- CSR fill ----
        int e = (blockIdx.x - GEMM_BLOCKS) * 256 + tid;
        if (e < EE) {
            int src = ei[e];
            int dst = ei[EE + e];
            float2 a = *(const float2*)(ea + 2 * e);
            int rk = rank16[e];
            int c = rk >> 8, rl = rk & 255;
            int pos = row_start[dst] + (int)cnt_x[c * CSTR + dst] + rl;
            unsigned packed = ((unsigned)f2bf(a.y) << 16) | f2bf(a.x);
            edge_rec[pos] = make_uint2((unsigned)src, packed);
        }
        return;
    }

    // ---- GEMM ----
    // bijective chunked XCD swizzle: orig id = kk*8+xcd -> chunk(xcd) + kk
    int bid = blockIdx.x;
    const int q = GEMM_BLOCKS / 8, r = GEMM_BLOCKS % 8;     // 195, 4
    int xcd = bid & 7, kk = bid >> 3;
    int wg = (xcd < r) ? xcd * (q + 1) + kk
                       : r * (q + 1) + (xcd - r) * q + kk;

    int wid = tid >> 6, lane = tid & 63;
    int mt = wg >> 2, nt = wg & 3;
    int mBase = mt * 128, nBase = nt * 128;
    int wm = (wid & 1) * 64, wn = (wid >> 1) * 64;
    int qq4 = lane >> 4, mh = lane & 15;

    f32x4 acc[4][4];
#pragma unroll
    for (int i = 0; i < 4; ++i)
#pragma unroll
        for (int j = 0; j < 4; ++j)
            acc[i][j] = (f32x4){0.f, 0.f, 0.f, 0.f};

    int aoff[4], boff[4];
#pragma unroll
    for (int f = 0; f < 4; ++f) {
        int rr = wm + f * 16 + mh;
        aoff[f] = (rr * 4 + (qq4 ^ (rr & 3))) * 8;
        int nl = wn + f * 16 + mh;
        boff[f] = 4096 + (nl * 4 + (qq4 ^ (nl & 3))) * 8;
    }

    for (int k0 = 0; k0 < 256; k0 += 32) {
        __syncthreads();
#pragma unroll
        for (int it = 0; it < 4; ++it) {
            int L = it * 256 + tid;
            const unsigned short* g;
            if (L < 512) {
                int rr = L >> 2;
                int q2 = (L & 3) ^ (rr & 3);
                int grow = mBase + rr;
                if (grow > NN - 1) grow = NN - 1;
                g = xb + (size_t)grow * 256 + k0 + q2 * 8;
            } else {
                int LB = L - 512;
                int nl = LB >> 2;
                int q2 = (LB & 3) ^ (nl & 3);
                g = wt + (size_t)(nBase + nl) * 256 + k0 + q2 * 8;
            }
            short* lp = sAB + (it * 256 + wid * 64) * 8;
            __builtin_amdgcn_global_load_lds(
                (const __attribute__((address_space(1))) void*)g,
                (__attribute__((address_space(3))) void*)lp, 16, 0, 0);
        }
        __syncthreads();

        short8 af[4], bfr[4];
#pragma unroll
        for (int f = 0; f < 4; ++f) af[f]  = *(const short8*)(sAB + aoff[f]);
#pragma unroll
        for (int f = 0; f < 4; ++f) bfr[f] = *(const short8*)(sAB + boff[f]);
#pragma unroll
        for (int i = 0; i < 4; ++i)
#pragma unroll
            for (int j = 0; j < 4; ++j)
                acc[i][j] = __builtin_amdgcn_mfma_f32_16x16x32_bf16(
                    af[i], bfr[j], acc[i][j], 0, 0, 0);
    }

    // split C-write: nt<2 -> xl, nt>=2 -> xr; col-in-half = (nt&1)*128 + ...
    unsigned short* cb = (nt < 2) ? xl : xr;
    int chalf = (nt & 1) * 128;
#pragma unroll
    for (int i = 0; i < 4; ++i)
#pragma unroll
        for (int j = 0; j < 4; ++j)
#pragma unroll
            for (int rr = 0; rr < 4; ++rr) {
                int row = mBase + wm + i * 16 + qq4 * 4 + rr;
                if (row < NN) {
                    int col = chalf + wn + j * 16 + mh;
                    cb[(size_t)row * 256 + col] = f2bf(acc[i][j][rr]);
                }
            }
}

// ---------------------------------------------------------------------------
// K5: fused attention — one wave per dst node (round-6 verified, UNCHANGED:
// depth-8 register-renamed gather ring, chunk-cached edge records + readlane,
// DPP 8-lane reduction, packed-fp32 math). Control group this round.
// ---------------------------------------------------------------------------
__global__ __launch_bounds__(256) void k_attn(
    const unsigned short* __restrict__ xl, const unsigned short* __restrict__ xr,
    const int* __restrict__ row_start, const uint2* __restrict__ edge_rec,
    const float* __restrict__ W_e, const float* __restrict__ att,
    const float* __restrict__ bias, float* __restrict__ out)
{
    int n = __builtin_amdgcn_readfirstlane(blockIdx.x * 4 + (threadIdx.x >> 6));
    if (n >= NN) return;
    int lane = threadIdx.x & 63;
    int j = lane * 4;

    uint2 xru = *(const uint2*)(xr + ((size_t)n << 8) + j);
    v2f xr01 = {u2f_lo(xru.x), u2f_hi(xru.x)};
    v2f xr23 = {u2f_lo(xru.y), u2f_hi(xru.y)};
    float4 av = *(const float4*)(att + j);
    v2f att01 = {av.x * LOG2E, av.y * LOG2E};
    v2f att23 = {av.z * LOG2E, av.w * LOG2E};
    float4 w0v = *(const float4*)(W_e + j);
    float4 w1v = *(const float4*)(W_e + 256 + j);
    v2f we0_01 = {w0v.x, w0v.y}, we0_23 = {w0v.z, w0v.w};
    v2f we1_01 = {w1v.x, w1v.y}, we1_23 = {w1v.z, w1v.w};
    const v2f sl2 = {NEG_SLOPE, NEG_SLOPE};

    int rs = __builtin_amdgcn_readfirstlane(row_start[n]);
    int cn = __builtin_amdgcn_readfirstlane(row_start[n + 1]) - rs;

    float D = 0.0f, la0 = 0.0f, la1 = 0.0f;
    v2f acc01 = {0.f, 0.f}, acc23 = {0.f, 0.f};

    auto body = [&](uint2 ru, float a0, float a1) {
        v2f xl01 = {u2f_lo(ru.x), u2f_hi(ru.x)};
        v2f xl23 = {u2f_lo(ru.y), u2f_hi(ru.y)};
        v2f a0v = {a0, a0}, a1v = {a1, a1};
        v2f m01 = xl01 + xr01;
        v2f m23 = xl23 + xr23;
        m01 = __builtin_elementwise_fma(a0v, we0_01, m01);
        m23 = __builtin_elementwise_fma(a0v, we0_23, m23);
        m01 = __builtin_elementwise_fma(a1v, we1_01, m01);
        m23 = __builtin_elementwise_fma(a1v, we1_23, m23);
        v2f t01 = __builtin_elementwise_max(m01, m01 * sl2);
        v2f t23 = __builtin_elementwise_max(m23, m23 * sl2);
        v2f sv = t01 * att01;
        sv = __builtin_elementwise_fma(t23, att23, sv);
        float s = sv.x + sv.y;
        s = red8(s);
        float w = __builtin_amdgcn_exp2f(s);
        D += w;
        v2f wv = {w, w};
        acc01 = __builtin_elementwise_fma(wv, xl01, acc01);
        acc23 = __builtin_elementwise_fma(wv, xl23, acc23);
    };

    int done = 0;
    while (done < cn) {
        int m = cn - done; if (m > 64) m = 64;
        int ridx = rs + done + lane;
        if (ridx > EE + 63) ridx = EE + 63;          // zeroed pad region
        uint2 rc = edge_rec[ridx];
        int rcx = (int)rc.x, rca = (int)rc.y;

        auto gat = [&](int k) -> uint2 {             // k is wave-uniform
            unsigned sidx = (unsigned)__builtin_amdgcn_readlane(rcx, k);
            return *(const uint2*)(xl + ((size_t)sidx << 8) + j);
        };
        auto proc = [&](uint2 xu, int k) {
            unsigned pk = (unsigned)__builtin_amdgcn_readlane(rca, k);
            float a0 = __uint_as_float(pk << 16);
            float a1 = __uint_as_float(pk & 0xffff0000u);
            la0 += a0; la1 += a1;
            body(xu, a0, a1);
        };

        uint2 x0 = gat(0), x1 = gat(1), x2 = gat(2), x3 = gat(3);
        uint2 x4 = gat(4), x5 = gat(5), x6 = gat(6), x7 = gat(7);
        for (int i = 0; i < m; i += 8) {
            proc(x0, i);
            if (i +  8 < m) x0 = gat(i +  8);
            if (i + 1 < m) { proc(x1, i + 1); if (i +  9 < m) x1 = gat(i +  9); }
            if (i + 2 < m) { proc(x2, i + 2); if (i + 10 < m) x2 = gat(i + 10); }
            if (i + 3 < m) { proc(x3, i + 3); if (i + 11 < m) x3 = gat(i + 11); }
            if (i + 4 < m) { proc(x4, i + 4); if (i + 12 < m) x4 = gat(i + 12); }
            if (i + 5 < m) { proc(x5, i + 5); if (i + 13 < m) x5 = gat(i + 13); }
            if (i + 6 < m) { proc(x6, i + 6); if (i + 14 < m) x6 = gat(i + 14); }
            if (i + 7 < m) { proc(x7, i + 7); if (i + 15 < m) x7 = gat(i + 15); }
        }
        done += m;
    }

    // self loop last, with mean edge attr of incoming edges
    float invc = 1.0f / fmaxf((float)cn, 1.0f);
    uint2 xs = *(const uint2*)(xl + ((size_t)n << 8) + j);
    body(xs, la0 * invc, la1 * invc);

    float invD = 1.0f / D;
    float4 b4 = *(const float4*)(bias + j);
    float4 o;
    o.x = fmaf(acc01.x, invD, b4.x);
    o.y = fmaf(acc01.y, invD, b4.y);
    o.z = fmaf(acc23.x, invD, b4.z);
    o.w = fmaf(acc23.y, invD, b4.w);
    *(float4*)(out + (size_t)n * 256 + j) = o;
}

// ---------------------------------------------------------------------------
extern "C" void kernel_launch(void* const* d_in, const int* in_sizes, int n_in,
                              void* d_out, int out_size, void* d_ws, size_t ws_size,
                              hipStream_t stream)
{
    const float* x    = (const float*)d_in[0];
    const int*   ei   = (const int*)  d_in[1];
    const float* ea   = (const float*)d_in[2];
    const float* Wl   = (const float*)d_in[3];
    const float* Wr   = (const float*)d_in[4];
    const float* We   = (const float*)d_in[5];
    const float* att  = (const float*)d_in[6];
    const float* bias = (const float*)d_in[7];
    float* out = (float*)d_out;

    char* ws = (char*)d_ws;
    size_t off = 0;
    unsigned short* xl = (unsigned short*)(ws + off); off += (size_t)NN * 256 * 2;   // 25.6 MB
    unsigned short* xr = (unsigned short*)(ws + off); off += (size_t)NN * 256 * 2;   // 25.6 MB
    unsigned short* xb = (unsigned short*)(ws + off); off += (size_t)NN * 256 * 2;   // 25.6 MB
    uint2*  edge_rec   = (uint2*)(ws + off);          off += (size_t)(EE + 64) * 8;  //  6.4 MB (+512B pad)
    unsigned* cnt_x    = (unsigned*)(ws + off);       off += (size_t)8 * CSTR * 4;   //  1.6 MB (adjacent to pad)
    int*    row_st     = (int*)(ws + off);            off += (size_t)NPAD * 4;       //  tot -> scanned in place
    unsigned short* rank16 = (unsigned short*)(ws + off); off += (size_t)EE * 2;     //  1.6 MB
    unsigned short* wt = (unsigned short*)(ws + off); off += (size_t)512 * 256 * 2;  // 256 KB
    // total ~86.9 MB (<= round-6 footprint)

    // single memset zeroes the edge_rec prefetch pad AND the 8 partial arrays
    hipMemsetAsync(edge_rec + EE, 0,
                   64 * sizeof(uint2) + (size_t)8 * CSTR * 4, stream);

    k_prep_count<<<MIX_BLOCKS + WT_BLOCKS, 256, 0, stream>>>(
        x, Wl, Wr, ei, xb, wt, cnt_x, rank16);
    k_prered    <<<PRERED_BLOCKS, 256, 0, stream>>>(cnt_x, row_st);
    k_scan      <<<1, 1024, 0, stream>>>(row_st);
    k_gemm_fill <<<GEMM_BLOCKS + FILL_BLOCKS, 256, 0, stream>>>(
        xb, wt, ei, ea, row_st, rank16, cnt_x, xl, xr, edge_rec);
    k_attn      <<<12500, 256, 0, stream>>>(
        xl, xr, row_st, edge_rec, We, att, bias, out);
}